// Round 10
// baseline (199.928 us; speedup 1.0000x reference)
//
#include <hip/hip_runtime.h>

#define BB 4
#define CC 256
#define HIDD 128
#define NN 4096

typedef short s8v __attribute__((ext_vector_type(8)));
typedef _Float16 h8v __attribute__((ext_vector_type(8)));
typedef float f4v __attribute__((ext_vector_type(4)));
typedef unsigned int u4v __attribute__((ext_vector_type(4)));
typedef unsigned short u16b;

// ---- exp path (rounds 4-8 decomposition) ---------------------------------------
// measured: __expf fast path = baseline; libm exp2f = +7us (OCML precise);
// raw asm v_exp = NaN (no hazard handling around opaque asm). builtin exp2
// (when present) = single v_exp_f32 with hazard handling; all within noise of
// __expf, kept for the saved v_mul. Fallback reproduces round-4 exactly.
#if __has_builtin(__builtin_amdgcn_exp2f)
#define PHI_SCALE 1.44269504088896f    /* phi carries log2e; exp(s)=exp2(s') */
static __device__ __forceinline__ float fexp(float x) { return __builtin_amdgcn_exp2f(x); }
#else
#define PHI_SCALE 1.0f
static __device__ __forceinline__ float fexp(float x) { return __expf(x); }
#endif

static __device__ __forceinline__ float b2f(unsigned short u) {
    union { unsigned int i; float f; } v; v.i = ((unsigned int)u) << 16; return v.f;
}
static __device__ __forceinline__ unsigned short f2b(float f) {
    union { float f; unsigned int i; } v; v.f = f;
    unsigned int i = v.i;
    return (unsigned short)((i + 0x7fffu + ((i >> 16) & 1u)) >> 16);
}
static __device__ __forceinline__ u16b f2h_bits(float f) {
    union { _Float16 h; u16b u; } v; v.h = (_Float16)f; return v.u;
}
// packed RNE f32x2 -> bf16x2 (hardware cvt; 1 instr for 2 elements)
static __device__ __forceinline__ unsigned int cvt_pk_bf16(float lo, float hi) {
    unsigned int r;
    asm("v_cvt_pk_bf16_f32 %0, %1, %2" : "=v"(r) : "v"(lo), "v"(hi));
    return r;
}

// Standard swizzled fragment layout for 16x16x32 MFMA operands (16-bit dtypes).
__device__ __forceinline__ int swz(int k, int rc, int CB) {
    return (((k >> 5) * CB + (rc >> 4)) * 64 + ((k >> 3) & 3) * 16 + (rc & 15)) * 8 + (k & 7);
}
// Permuted swizzle for G': k-slot (q,j) <-> m_local = (j>>2)*16 + q*4 + (j&3).
__device__ __forceinline__ int gswz(int m, int o) {
    int kb = m >> 5, mm = m & 31;
    int qs = (mm >> 2) & 3;
    int js = ((mm >> 4) & 1) * 4 + (mm & 3);
    return ((kb * 8 + (o >> 4)) * 64 + qs * 16 + (o & 15)) * 8 + js;
}

// ---------- Phase 0: weights -> fp16 (theta/phi/g) and bf16 (mask) --------------
__global__ __launch_bounds__(256) void prep_kernel(
    const float* __restrict__ wt, const float* __restrict__ wp,
    const float* __restrict__ wg, const float* __restrict__ wm,
    u16b* __restrict__ wF, u16b* __restrict__ wmB)
{
    int t = blockIdx.x * 256 + threadIdx.x;   // grid 128 -> 32768 = HID*CC
    wF[t]         = f2h_bits(wt[t]);
    wF[32768 + t] = f2h_bits(wp[t] * PHI_SCALE);
    wF[65536 + t] = f2h_bits(wg[t]);
    wmB[t]        = f2b(wm[t]);
}

// ---------- Phase 1: Theta/Phi (fp16, swizzled) and G (bf16, perm-swizzled) -----
// All MFMAs fp16 single-pass (2^-11 operand precision).
__global__ __launch_bounds__(256) void proj_kernel(
    const float* __restrict__ x, const u16b* __restrict__ wF,
    u16b* __restrict__ thetaF, u16b* __restrict__ phiF, u16b* __restrict__ gB)
{
    int wave = blockIdx.x * 4 + (threadIdx.x >> 6);   // 2048 waves
    int lane = threadIdx.x & 63;
    int l15 = lane & 15, q = lane >> 4;
    int b = wave >> 9;
    int rem = wave & 511;
    int ntile = rem >> 1;
    int half = rem & 1;                                // ot range half*4..half*4+3
    int n0 = ntile << 4;
    const float* xb = x + (size_t)b * CC * NN;

    f4v acc[3][4];
#pragma unroll
    for (int m = 0; m < 3; m++)
#pragma unroll
        for (int i = 0; i < 4; i++) acc[m][i] = (f4v){0.f, 0.f, 0.f, 0.f};

    float xv[8];
    {
        const float* xp = xb + (size_t)(q * 8) * NN + n0 + l15;
#pragma unroll
        for (int j = 0; j < 8; j++) xv[j] = xp[(size_t)j * NN];
    }

    for (int kc = 0; kc < 8; kc++) {
        int c0 = kc * 32;
        float xn[8];
        if (kc < 7) {
            const float* xp = xb + (size_t)(c0 + 32 + q * 8) * NN + n0 + l15;
#pragma unroll
            for (int j = 0; j < 8; j++) xn[j] = xp[(size_t)j * NN];
        }
        h8v bx;
#pragma unroll
        for (int j = 0; j < 8; j++) bx[j] = (_Float16)xv[j];
#pragma unroll
        for (int mat = 0; mat < 3; mat++) {
#pragma unroll
            for (int otl = 0; otl < 4; otl++) {
                int ot = half * 4 + otl;
                const h8v* ap = reinterpret_cast<const h8v*>(
                    wF + mat * 32768 + (ot * 16 + l15) * CC + c0 + q * 8);
                acc[mat][otl] = __builtin_amdgcn_mfma_f32_16x16x32_f16(*ap, bx, acc[mat][otl], 0, 0, 0);
            }
        }
        if (kc < 7) {
#pragma unroll
            for (int j = 0; j < 8; j++) xv[j] = xn[j];
        }
    }

    size_t boff = (size_t)b * (NN * HIDD);
#pragma unroll
    for (int otl = 0; otl < 4; otl++) {
#pragma unroll
        for (int r = 0; r < 4; r++) {
            int o = (half * 4 + otl) * 16 + q * 4 + r;   // C/D row (hid)
            int n = n0 + l15;                             // C/D col (spatial)
            int offTP = swz(o, n, NN / 16);
            thetaF[boff + offTP] = f2h_bits(acc[0][otl][r]);
            phiF[boff + offTP]   = f2h_bits(acc[1][otl][r]);
            gB[boff + gswz(n, o)] = f2b(acc[2][otl][r]);  // bf16: G' needs range
        }
    }
}

// ---------- small path Phase 2: Lraw[m] = sum_n e^{s[n][m]} (fp16 S) ------------
__global__ __launch_bounds__(256, 2) void stats_kernel(
    const u16b* __restrict__ thetaF, const u16b* __restrict__ phiF,
    float* __restrict__ Lraw)
{
    int xcd = blockIdx.x & 7;                  // grid 1024
    int inner = blockIdx.x >> 3;               // 0..127
    int b = xcd >> 1;
    int su = (xcd & 1) * 128 + inner;          // 0..255 within batch
    int w = threadIdx.x >> 6;
    int wu = su * 4 + w;                       // 0..1023
    int mg = wu >> 4;                          // 64 groups of 4 mtiles
    int ns = wu & 15;                          // 16-way n-split
    int lane = threadIdx.x & 63;

    size_t boff = (size_t)b * (NN * HIDD);
    const u16b* thF = thetaF + boff;
    const u16b* phF = phiF + boff;

    h8v pB[4][4];
#pragma unroll
    for (int mt = 0; mt < 4; mt++)
#pragma unroll
        for (int kb = 0; kb < 4; kb++)
            pB[mt][kb] = *reinterpret_cast<const h8v*>(phF + ((kb * 256 + (mg * 4 + mt)) * 64 + lane) * 8);

    float Lp[4];
#pragma unroll
    for (int i = 0; i < 4; i++) Lp[i] = 0.f;

    for (int i = 0; i < 16; i++) {
        int ntile = ns * 16 + i;
        h8v tA[4];
#pragma unroll
        for (int kb = 0; kb < 4; kb++)
            tA[kb] = *reinterpret_cast<const h8v*>(thF + ((kb * 256 + ntile) * 64 + lane) * 8);
#pragma unroll
        for (int mt = 0; mt < 4; mt++) {
            f4v s = (f4v){0.f, 0.f, 0.f, 0.f};
#pragma unroll
            for (int kb = 0; kb < 4; kb++)
                s = __builtin_amdgcn_mfma_f32_16x16x32_f16(tA[kb], pB[mt][kb], s, 0, 0, 0);
            Lp[mt] += (fexp(s[0]) + fexp(s[1])) + (fexp(s[2]) + fexp(s[3]));
        }
    }
#pragma unroll
    for (int mt = 0; mt < 4; mt++) {
        float v = Lp[mt];
        v += __shfl_xor(v, 16);
        v += __shfl_xor(v, 32);
        if (lane < 16) atomicAdd(&Lraw[b * NN + (mg * 4 + mt) * 16 + lane], v);
    }
}

// ---------- small path Phase 2b: G'[m,o] = G[m,o] / L[m] ------------------------
__global__ __launch_bounds__(256) void rescale_kernel(
    u16b* __restrict__ gB, const float* __restrict__ Lraw)
{
    int t = blockIdx.x * 256 + threadIdx.x;    // grid 1024
    int flat0 = t * 8;
    int b = flat0 >> 19;
    int rem = flat0 & ((NN * HIDD) - 1);
    int kb = rem >> 12;
    int lane = (rem >> 3) & 63;
    int qs = lane >> 4;
    int mbase = kb * 32 + qs * 4;
    const float* Lp = Lraw + b * NN + mbase;
    u16b* gp = gB + flat0;
    s8v g = *reinterpret_cast<const s8v*>(gp);
    s8v o;
#pragma unroll
    for (int j = 0; j < 8; j++) {
        float v = b2f((unsigned short)g[j]) / Lp[((j >> 2) << 4) + (j & 3)];
        o[j] = (short)f2b(v);
    }
    *reinterpret_cast<s8v*>(gp) = o;
}

// ---------- small path Phase 3: Out += softmax(S) @ G' (fp16 S, bf16 PV) --------
__global__ __launch_bounds__(256, 2) void attn_kernel(
    const u16b* __restrict__ thetaF, const u16b* __restrict__ phiF,
    const u16b* __restrict__ gB, float* __restrict__ outAcc)
{
    int xcd = blockIdx.x & 7;                  // grid 1024
    int inner = blockIdx.x >> 3;               // 0..127
    int combo = xcd * 4 + (inner & 3);         // 0..31 = b*8+ms (XCD-pinned)
    int b = combo >> 3;
    int ms = combo & 7;                        // 8-way m-split
    int ng = inner >> 2;                       // 0..31
    int w = threadIdx.x >> 6;
    int lane = threadIdx.x & 63;
    int l15 = lane & 15, q = lane >> 4;
    int ntile0 = ng * 8 + w * 2;

    size_t boff = (size_t)b * (NN * HIDD);
    const u16b* thF = thetaF + boff;
    const u16b* phF = phiF + boff;
    const u16b* gp = gB + boff;

    h8v tB[2][4];
#pragma unroll
    for (int nt = 0; nt < 2; nt++)
#pragma unroll
        for (int kb = 0; kb < 4; kb++)
            tB[nt][kb] = *reinterpret_cast<const h8v*>(thF + ((kb * 256 + ntile0 + nt) * 64 + lane) * 8);

    f4v acc[2][8];
#pragma unroll
    for (int nt = 0; nt < 2; nt++)
#pragma unroll
        for (int i = 0; i < 8; i++) acc[nt][i] = (f4v){0.f, 0.f, 0.f, 0.f};

    for (int mt = 0; mt < 16; mt++) {
        int m0 = ms * 512 + mt * 32;
        s8v pf[2];
#pragma unroll
        for (int h = 0; h < 2; h++) {
            int mtile = (m0 >> 4) + h;
            h8v pA[4];
#pragma unroll
            for (int kb = 0; kb < 4; kb++)
                pA[kb] = *reinterpret_cast<const h8v*>(phF + ((kb * 256 + mtile) * 64 + lane) * 8);
#pragma unroll
            for (int nt = 0; nt < 2; nt++) {
                f4v s = (f4v){0.f, 0.f, 0.f, 0.f};
#pragma unroll
                for (int kb = 0; kb < 4; kb++)
                    s = __builtin_amdgcn_mfma_f32_16x16x32_f16(pA[kb], tB[nt][kb], s, 0, 0, 0);
#pragma unroll
                for (int r = 0; r < 4; r++)
                    pf[nt][h * 4 + r] = (short)f2b(fexp(s[r]));
            }
        }
        int kb2 = m0 >> 5;
#pragma unroll
        for (int ot = 0; ot < 8; ot++) {
            s8v gf = *reinterpret_cast<const s8v*>(gp + ((kb2 * 8 + ot) * 64 + lane) * 8);
#pragma unroll
            for (int nt = 0; nt < 2; nt++)
                acc[nt][ot] = __builtin_amdgcn_mfma_f32_16x16x32_bf16(pf[nt], gf, acc[nt][ot], 0, 0, 0);
        }
    }

    float* oa = outAcc + (size_t)b * (NN * HIDD);
#pragma unroll
    for (int nt = 0; nt < 2; nt++) {
        int n_base = (ntile0 + nt) * 16;
#pragma unroll
        for (int ot = 0; ot < 8; ot++) {
#pragma unroll
            for (int r = 0; r < 4; r++) {
                int n = n_base + q * 4 + r;
                int o = ot * 16 + l15;
                atomicAdd(&oa[swz(o, n, NN / 16)], acc[nt][ot][r]);
            }
        }
    }
}

// ---------- big path Phase 2: S-pass fp16, pipelined, full 16B P stores ---------
// v8: round-4 structure + NON-TEMPORAL P stores. The poison fill proves pure
// streaming writes reach 6.6 TB/s; spass got 3.6. Theory: the 134 MB P stream
// write-allocates through each XCD's 4 MB L2, evicting the theta/phi working
// set every i2. nt stores bypass L2 allocation -> theta/phi stay resident.
__global__ __launch_bounds__(256, 4) void spass_kernel(
    const u16b* __restrict__ thetaF, const u16b* __restrict__ phiF,
    u16b* __restrict__ P, float* __restrict__ Lpart)
{
    int xcd = blockIdx.x & 7;                  // grid 2048
    int inner = blockIdx.x >> 3;               // 0..255
    int combo = xcd * 8 + (inner & 7);         // 0..63 = b*16+ms
    int b = combo >> 4;
    int ms = combo & 15;                       // 16-way m-split
    int ng = inner >> 3;                       // 0..31
    int w = threadIdx.x >> 6;
    int lane = threadIdx.x & 63;
    int l15 = lane & 15, q = lane >> 4;
    int ntile0 = ng * 8 + w * 2;

    size_t boff = (size_t)b * (NN * HIDD);
    const u16b* thF = thetaF + boff;
    const u16b* phF = phiF + boff;
    u16b* Pb = P + (size_t)b * NN * NN;

    // [w][m_local(256)][group(4)] stride 5 words. 20 KB.
    __shared__ float Lacc3[4 * 256 * 5];

    h8v tB[2][4];
#pragma unroll
    for (int nt = 0; nt < 2; nt++)
#pragma unroll
        for (int kb = 0; kb < 4; kb++)
            tB[nt][kb] = *reinterpret_cast<const h8v*>(thF + ((kb * 256 + ntile0 + nt) * 64 + lane) * 8);

    int ph = ng & 7;                           // stagger phase (kb2 granularity)
    h8v pA[4];
    {
        int mtile = ms * 16 + ph * 2;          // i2=0, h=0
#pragma unroll
        for (int kb = 0; kb < 4; kb++)
            pA[kb] = *reinterpret_cast<const h8v*>(phF + ((kb * 256 + mtile) * 64 + lane) * 8);
    }

    for (int i2 = 0; i2 < 8; i2++) {
        int mtr = (i2 + ph) & 7;
        unsigned int p000, p001, p010, p011;   // nt=0: h0 pair, h1 pair
        unsigned int p100, p101, p110, p111;   // nt=1
#pragma unroll
        for (int h = 0; h < 2; h++) {
            // prefetch next half-tile's phi (wraps harmlessly on last iter)
            int nmtile = (h == 0) ? (ms * 16 + mtr * 2 + 1)
                                  : (ms * 16 + (((i2 + 1 + ph) & 7)) * 2);
            h8v pAN[4];
#pragma unroll
            for (int kb = 0; kb < 4; kb++)
                pAN[kb] = *reinterpret_cast<const h8v*>(phF + ((kb * 256 + nmtile) * 64 + lane) * 8);
            // S^T tile for both ntiles (fp16, interleaved)
            f4v s0 = (f4v){0.f, 0.f, 0.f, 0.f};
            f4v s1 = (f4v){0.f, 0.f, 0.f, 0.f};
#pragma unroll
            for (int kb = 0; kb < 4; kb++) {
                s0 = __builtin_amdgcn_mfma_f32_16x16x32_f16(pA[kb], tB[0][kb], s0, 0, 0, 0);
                s1 = __builtin_amdgcn_mfma_f32_16x16x32_f16(pA[kb], tB[1][kb], s1, 0, 0, 0);
            }
            float ev0[4], ev1[4];
#pragma unroll
            for (int r = 0; r < 4; r++) {
                ev0[r] = fexp(s0[r]);
                ev1[r] = fexp(s1[r]);
            }
            // packed HW bf16 convert (RNE), 1 instr per 2 values
            if (h == 0) {
                p000 = cvt_pk_bf16(ev0[0], ev0[1]);
                p001 = cvt_pk_bf16(ev0[2], ev0[3]);
                p100 = cvt_pk_bf16(ev1[0], ev1[1]);
                p101 = cvt_pk_bf16(ev1[2], ev1[3]);
            } else {
                p010 = cvt_pk_bf16(ev0[0], ev0[1]);
                p011 = cvt_pk_bf16(ev0[2], ev0[3]);
                p110 = cvt_pk_bf16(ev1[0], ev1[1]);
                p111 = cvt_pk_bf16(ev1[2], ev1[3]);
            }
            // column partial: nt-sum, then 2-stage shfl reduce over l15 pairs
            int tloc = mtr * 32 + h * 16 + q * 4;
            float cs[4];
#pragma unroll
            for (int r = 0; r < 4; r++) {
                cs[r] = ev0[r] + ev1[r];
                cs[r] += __shfl_xor(cs[r], 1);
                cs[r] += __shfl_xor(cs[r], 2);
            }
            if ((l15 & 3) == 0) {
#pragma unroll
                for (int r = 0; r < 4; r++)
                    Lacc3[(w * 256 + tloc + r) * 5 + (l15 >> 2)] = cs[r];
            }
            // rotate prefetch registers
#pragma unroll
            for (int kb = 0; kb < 4; kb++) pA[kb] = pAN[kb];
        }
        // full 16B nt store per kb2 (both halves assembled); P is write-once,
        // read-once by pv -> bypass L2 allocation
        int kb2 = ms * 8 + mtr;
        u4v pf0 = (u4v){p000, p001, p010, p011};
        u4v pf1 = (u4v){p100, p101, p110, p111};
        __builtin_nontemporal_store(pf0,
            reinterpret_cast<u4v*>(Pb + ((size_t)(kb2 * 256 + ntile0 + 0) * 64 + lane) * 8));
        __builtin_nontemporal_store(pf1,
            reinterpret_cast<u4v*>(Pb + ((size_t)(kb2 * 256 + ntile0 + 1) * 64 + lane) * 8));
    }
    __syncthreads();
    {
        int t = threadIdx.x;                   // 0..255 == m_local
        float s = 0.f;
#pragma unroll
        for (int w4 = 0; w4 < 4; w4++) {
            float ps = 0.f;
#pragma unroll
            for (int j = 0; j < 4; j++)
                ps += Lacc3[(w4 * 256 + t) * 5 + j];
            s += ps;
        }
        Lpart[((size_t)(combo * 32 + ng)) * 256 + t] = s;
    }
}

// ---------- big path Phase 2b: fused L-sum + G rescale --------------------------
__global__ __launch_bounds__(256) void lrescale_kernel(
    u16b* __restrict__ gB, const float* __restrict__ Lpart)
{
    int t = blockIdx.x;                        // grid 1024
    int b = t >> 8;
    int kb = (t & 255) >> 1;                   // m>>5, 0..127
    int combo = b * 16 + (kb >> 3);
    int mlbase = (kb & 7) * 32;
    __shared__ float sLp[32][9];
    __shared__ float sL[32];
    int ti = threadIdx.x;
    {
        int mi = ti & 31;                      // = qs*8 + h*4 + r
        int ngp = ti >> 5;                     // 0..7
        int qs = mi >> 3, h = (mi >> 2) & 1, r = mi & 3;
        int ml = mlbase + qs * 4 + h * 16 + r;
        const float* base = Lpart + ((size_t)(combo * 32 + ngp * 4)) * 256 + ml;
        sLp[mi][ngp] = (base[0] + base[256]) + (base[512] + base[768]);
    }
    __syncthreads();
    if (ti < 32) {
        float s = 0.f;
#pragma unroll
        for (int k = 0; k < 8; k++) s += sLp[ti][k];
        sL[ti] = s;
    }
    __syncthreads();
    size_t flat0 = (size_t)b * (NN * HIDD) + (size_t)(t & 255) * 2048 + (size_t)ti * 8;
    int lane = ti & 63;
    int qs = lane >> 4;
    u16b* gp = gB + flat0;
    s8v g = *reinterpret_cast<const s8v*>(gp);
    s8v o;
#pragma unroll
    for (int j = 0; j < 8; j++) {
        int mi = qs * 8 + ((j >> 2) << 2) + (j & 3);
        float v = b2f((unsigned short)g[j]) / sL[mi];
        o[j] = (short)f2b(v);
    }
    *reinterpret_cast<s8v*>(gp) = o;
}

// ---------- big path Phase 3: partial[ms] = P-slice @ G' (NO atomics) -----------
// v3 structure (measured ~31 us) + NON-TEMPORAL P loads: P is read-once
// streaming (134 MB); nt keeps it from evicting the g fragments every block
// re-reads 32x from L2. pvPart store also nt (read-once by final_big).
__global__ __launch_bounds__(256, 3) void pv_kernel(
    const u16b* __restrict__ P, const u16b* __restrict__ gB, u16b* __restrict__ pvPart)
{
    int xcd = blockIdx.x & 7;                  // grid 1024
    int inner = blockIdx.x >> 3;               // 0..127
    int combo = xcd * 2 + (inner & 1);         // 0..15 = b*4+ms (XCD-pinned)
    int b = combo >> 2;
    int ms = combo & 3;                        // 4-way m-split
    int ng = inner >> 1;                       // 0..63
    int w = threadIdx.x >> 6;
    int lane = threadIdx.x & 63;
    int l15 = lane & 15, q = lane >> 4;
    int ntile = ng * 4 + w;                    // 0..255, one ntile per wave

    const u16b* Pb = P + (size_t)b * NN * NN;
    const u16b* gp = gB + (size_t)b * (NN * HIDD);

    __shared__ __align__(16) u16b gS[4 * 8 * 512];   // 4 slots x 8 frags x 1KB = 32 KB

    f4v acc[8];
#pragma unroll
    for (int i = 0; i < 8; i++) acc[i] = (f4v){0.f, 0.f, 0.f, 0.f};

    int ph = ng & 31;                          // stagger phase
    int ot0 = w * 2;                           // this wave's 2 g fragments

    s8v p0, p1, p2, p3;                        // static P ring (rule #20)

#define PV_KB2(it) (ms * 32 + (((it) + ph) & 31))
#define PV_ISSUE(it, sl, preg) do {                                              \
    int kb2_ = PV_KB2(it);                                                       \
    const u16b* s0_ = gp + (((size_t)(kb2_ * 8 + ot0) * 64 + lane) * 8);         \
    __builtin_amdgcn_global_load_lds(                                            \
        (const __attribute__((address_space(1))) unsigned int*)s0_,              \
        (__attribute__((address_space(3))) unsigned int*)(&gS[((sl) * 8 + ot0) * 512]), \
        16, 0, 0);                                                               \
    __builtin_amdgcn_global_load_lds(                                            \
        (const __attribute__((address_space(1))) unsigned int*)(s0_ + 512),      \
        (__attribute__((address_space(3))) unsigned int*)(&gS[((sl) * 8 + ot0 + 1) * 512]), \
        16, 0, 0);                                                               \
    preg = __builtin_nontemporal_load(reinterpret_cast<const s8v*>(              \
        Pb + ((size_t)(kb2_ * 256 + ntile) * 64 + lane) * 8));                   \
} while (0)

#define PV_STEP(it, sl, pcons, pnew) do {                                        \
    PV_ISSUE((it) + 2, ((sl) + 2) & 3, pnew);                                    \
    __builtin_amdgcn_sched_barrier(0);                                           \
    asm volatile("s_waitcnt vmcnt(6)" ::: "memory");                             \
    __builtin_amdgcn_sched_barrier(0);                                           \
    __builtin_amdgcn_s_barrier();                                                \
    __builtin_amdgcn_sched_barrier(0);                                           \
    const s8v* gs_ = reinterpret_cast<const s8v*>(gS) + (sl) * 512 + lane;       \
    s8v g0_ = gs_[0];   s8v g1_ = gs_[64];  s8v g2_ = gs_[128]; s8v g3_ = gs_[192]; \
    s8v g4_ = gs_[256]; s8v g5_ = gs_[320]; s8v g6_ = gs_[384]; s8v g7_ = gs_[448]; \
    acc[0] = __builtin_amdgcn_mfma_f32_16x16x32_bf16(pcons, g0_, acc[0], 0, 0, 0); \
    acc[1] = __builtin_amdgcn_mfma_f32_16x16x32_bf16(pcons, g1_, acc[1], 0, 0, 0); \
    acc[2] = __builtin_amdgcn_mfma_f32_16x16x32_bf16(pcons, g2_, acc[2], 0, 0, 0); \
    acc[3] = __builtin_amdgcn_mfma_f32_16x16x32_bf16(pcons, g3_, acc[3], 0, 0, 0); \
    acc[4] = __builtin_amdgcn_mfma_f32_16x16x32_bf16(pcons, g4_, acc[4], 0, 0, 0); \
    acc[5] = __builtin_amdgcn_mfma_f32_16x16x32_bf16(pcons, g5_, acc[5], 0, 0, 0); \
    acc[6] = __builtin_amdgcn_mfma_f32_16x16x32_bf16(pcons, g6_, acc[6], 0, 0, 0); \
    acc[7] = __builtin_amdgcn_mfma_f32_16x16x32_bf16(pcons, g7_, acc[7], 0, 0, 0); \
} while (0)

    // prologue: 2 iterations in flight (6 VMEM ops)
    PV_ISSUE(0, 0, p0);
    PV_ISSUE(1, 1, p1);

    for (int i8 = 0; i8 < 32; i8 += 4) {
        PV_STEP(i8 + 0, 0, p0, p2);
        PV_STEP(i8 + 1, 1, p1, p3);
        PV_STEP(i8 + 2, 2, p2, p0);
        PV_STEP(i8 + 3, 3, p3, p1);
    }
#undef PV_STEP
#undef PV_ISSUE
#undef PV_KB2

    u16b* pp = pvPart + (size_t)ms * ((size_t)BB * NN * HIDD) + (size_t)b * (NN * HIDD);
    int n_base = ntile * 16;
#pragma unroll
    for (int ot = 0; ot < 8; ot++) {
#pragma unroll
        for (int r = 0; r < 4; r++) {
            int n = n_base + q * 4 + r;
            int o = ot * 16 + l15;
            __builtin_nontemporal_store(f2b(acc[ot][r]), &pp[swz(o, n, NN / 16)]);
        }
    }
}

// ---------- big path Phase 4: y = x + w_mask @ (sum of partials)^T --------------
__global__ __launch_bounds__(256) void final_big_kernel(
    const float* __restrict__ x, const u16b* __restrict__ wmB,
    const u16b* __restrict__ pvPart, float* __restrict__ y)
{
    int wave = blockIdx.x * 4 + (threadIdx.x >> 6);   // 4096 waves
    int lane = threadIdx.x & 63;
    int l15 = lane & 15, q = lane >> 4;
    int b = wave >> 10;
    int rem = wave & 1023;
    int ctile = rem >> 6;
    int n64 = rem & 63;
    const size_t pstride = (size_t)BB * NN * HIDD;
    const u16b* pb = pvPart + (size_t)b * (NN * HIDD);
    const float* xb = x + (size_t)b * CC * NN;
    float* yb = y + (size_t)b * CC * NN;
    int c0 = ctile * 16;

    s8v aB[4];
#pragma unroll
    for (int kb = 0; kb < 4; kb++)
        aB[kb] = *reinterpret_cast<const s8v*>(wmB + (c0 + l15) * HIDD + kb * 32 + q * 8);

#pragma unroll
    for (int nt = 0; nt < 4; nt++) {
        int ntile = n64 * 4 + nt;
        f4v acc = (f4v){0.f, 0.f, 0.f, 0.f};
#pragma unroll
        for (int kb = 0; kb < 4; kb++) {
            size_t fo = ((size_t)(kb * 256 + ntile) * 64 + lane) * 8;
            // issue all 4 partial loads together (nt: read-once), convert+sum
            s8v v0 = __builtin_nontemporal_load(reinterpret_cast<const s8v*>(pb + 0 * pstride + fo));
            s8v v1 = __builtin_nontemporal_load(reinterpret_cast<const s8v*>(pb + 1 * pstride + fo));
            s8v v2 = __builtin_nontemporal_load(reinterpret_cast<const s8v*>(pb + 2 * pstride + fo));
            s8v v3 = __builtin_nontemporal_load(reinterpret_cast<const s8v*>(pb + 3 * pstride + fo));
            s8v bv;
#pragma unroll
            for (int j = 0; j < 8; j++) {
                float s = (b2f((unsigned short)v0[j]) + b2f((unsigned short)v1[j]))
                        + (b2f((unsigned short)v2[j]) + b2f((unsigned short)v3[j]));
                bv[j] = (short)f2b(s);
            }
            acc = __builtin_amdgcn_mfma_f32_16x16x32_bf16(aB[kb], bv, acc, 0, 0, 0);
        }
#pragma unroll
        for (int r = 0; r < 4; r++) {
            int c = c0 + q * 4 + r;
            int n = ntile * 16 + l15;
            size_t idx = (size_t)c * NN + n;
            yb[idx] = xb[idx] + acc[r];
        }
    }
}

// ---------- small path Phase 4: y = x + w_mask @ Out^T --------------------------
__global__ __launch_bounds__(256) void final_kernel(
    const float* __restrict__ x, const u16b* __restrict__ wmB,
    const float* __restrict__ outAcc, float* __restrict__ y)
{
    int wave = blockIdx.x * 4 + (threadIdx.x >> 6);   // 4096 waves
    int lane = threadIdx.x & 63;
    int l15 = lane & 15, q = lane >> 4;
    int b = wave >> 10;
    int rem = wave & 1023;
    int ctile = rem >> 6;
    int n64 = rem & 63;
    const float* oa = outAcc + (size_t)b * (NN * HIDD);
    const float* xb = x + (size_t)b * CC * NN;
    float* yb = y + (size_t)b * CC * NN;
    int c0 = ctile * 16;

    s8v aB[4];
#pragma unroll
    for (int kb = 0; kb < 4; kb++)
        aB[kb] = *reinterpret_cast<const s8v*>(wmB + (c0 + l15) * HIDD + kb * 32 + q * 8);

#pragma unroll
    for (int nt = 0; nt < 4; nt++) {
        int ntile = n64 * 4 + nt;
        f4v acc = (f4v){0.f, 0.f, 0.f, 0.f};
#pragma unroll
        for (int kb = 0; kb < 4; kb++) {
            const float* bp = oa + ((size_t)(kb * 256 + ntile) * 64 + lane) * 8;
            f4v b0 = *reinterpret_cast<const f4v*>(bp);
            f4v b1 = *reinterpret_cast<const f4v*>(bp + 4);
            s8v bv;
#pragma unroll
            for (int j = 0; j < 4; j++) {
                bv[j]     = (short)f2b(b0[j]);
                bv[j + 4] = (short)f2b(b1[j]);
            }
            acc = __builtin_amdgcn_mfma_f32_16x16x32_bf16(aB[kb], bv, acc, 0, 0, 0);
        }
#pragma unroll
        for (int r = 0; r < 4; r++) {
            int c = c0 + q * 4 + r;
            int n = ntile * 16 + l15;
            size_t idx = (size_t)c * NN + n;
            yb[idx] = xb[idx] + acc[r];
        }
    }
}

extern "C" void kernel_launch(void* const* d_in, const int* in_sizes, int n_in,
                              void* d_out, int out_size, void* d_ws, size_t ws_size,
                              hipStream_t stream)
{
    (void)in_sizes; (void)n_in; (void)out_size;
    const float* x  = (const float*)d_in[0];
    const float* wt = (const float*)d_in[1];
    const float* wp = (const float*)d_in[2];
    const float* wg = (const float*)d_in[3];
    const float* wm = (const float*)d_in[4];
    float* y = (float*)d_out;

    char* ws = (char*)d_ws;
    const size_t MB = 1 << 20;
    u16b* thetaF = (u16b*)(ws + 0 * MB);                   // 4 MB
    u16b* phiF   = (u16b*)(ws + 4 * MB);                   // 4 MB
    u16b* pvPart = (u16b*)(ws + 0 * MB);                   // 16 MB, overlays theta/phi (dead after spass)
    u16b* gB     = (u16b*)(ws + 16 * MB);                  // 4 MB
    float* outAcc = (float*)(ws + 20 * MB);                // 8 MB fp32 (small path)
    float* Lraw   = (float*)(ws + 28 * MB);                // 64 KB (small path)
    char* wbase = ws + 28 * MB + (64 << 10);
    u16b* wF  = (u16b*)(wbase);                            // 192 KB (theta+phi+g fp16)
    u16b* wmB = (u16b*)(wbase + (192 << 10));              // 64 KB
    float* Lpart = (float*)(ws + 30 * MB);                 // 2 MB (big path)
    u16b* P   = (u16b*)(ws + 32 * MB);                     // 134.2 MB (big path)

    const size_t need_big = 32 * MB + (size_t)BB * NN * NN * sizeof(u16b);
    const bool big = ws_size >= need_big;

    hipLaunchKernelGGL(prep_kernel, dim3(128), dim3(256), 0, stream,
                       wt, wp, wg, wm, wF, wmB);
    hipLaunchKernelGGL(proj_kernel, dim3(512), dim3(256), 0, stream,
                       x, wF, thetaF, phiF, gB);

    if (big) {
        hipLaunchKernelGGL(spass_kernel,    dim3(2048), dim3(256), 0, stream,
                           thetaF, phiF, P, Lpart);
        hipLaunchKernelGGL(lrescale_kernel, dim3(1024), dim3(256), 0, stream, gB, Lpart);
        // pv overwrites the theta/phi region (dead after spass) with bf16 partials
        hipLaunchKernelGGL(pv_kernel,       dim3(1024), dim3(256), 0, stream, P, gB, pvPart);
        hipLaunchKernelGGL(final_big_kernel, dim3(1024), dim3(256), 0, stream,
                           x, wmB, pvPart, y);
    } else {
        hipMemsetAsync(Lraw, 0, (size_t)BB * NN * sizeof(float), stream);
        hipMemsetAsync(outAcc, 0, (size_t)BB * NN * HIDD * sizeof(float), stream);
        hipLaunchKernelGGL(stats_kernel,   dim3(1024), dim3(256), 0, stream,
                           thetaF, phiF, Lraw);
        hipLaunchKernelGGL(rescale_kernel, dim3(1024), dim3(256), 0, stream, gB, Lraw);
        hipLaunchKernelGGL(attn_kernel,    dim3(1024), dim3(256), 0, stream,
                           thetaF, phiF, gB, outAcc);
        hipLaunchKernelGGL(final_kernel,   dim3(1024), dim3(256), 0, stream,
                           x, wmB, outAcc, y);
    }
}

// Round 11
// 174.204 us; speedup vs baseline: 1.1477x; 1.1477x over previous
//
#include <hip/hip_runtime.h>

#define BB 4
#define CC 256
#define HIDD 128
#define NN 4096

typedef short s8v __attribute__((ext_vector_type(8)));
typedef _Float16 h8v __attribute__((ext_vector_type(8)));
typedef float f4v __attribute__((ext_vector_type(4)));
typedef unsigned int u4v __attribute__((ext_vector_type(4)));
typedef unsigned short u16b;

// ---- exp path (rounds 4-8 decomposition) ---------------------------------------
// measured: __expf fast path = baseline; libm exp2f = +7us (OCML precise);
// raw asm v_exp = NaN (no hazard handling around opaque asm). builtin exp2
// (when present) = single v_exp_f32 with hazard handling; all within noise of
// __expf. Fallback reproduces the round-4 configuration exactly.
#if __has_builtin(__builtin_amdgcn_exp2f)
#define PHI_SCALE 1.44269504088896f    /* phi carries log2e; exp(s)=exp2(s') */
static __device__ __forceinline__ float fexp(float x) { return __builtin_amdgcn_exp2f(x); }
#else
#define PHI_SCALE 1.0f
static __device__ __forceinline__ float fexp(float x) { return __expf(x); }
#endif

// ---- cache-hint lesson (round 10) ----------------------------------------------
// NON-TEMPORAL hints on the P stream REGRESSED 181.8 -> 199.9us (pv 31 -> 42us).
// P (134 MB) FITS in the 256 MB Infinity Cache: normal stores leave it
// L3-resident and pv reads it back at L3 bandwidth. nt bypasses allocation in
// the whole hierarchy (not just L2), forcing a 268 MB pure-HBM round-trip.
// Do NOT nt-hint an intermediate that fits in L3 and is re-read later.

static __device__ __forceinline__ float b2f(unsigned short u) {
    union { unsigned int i; float f; } v; v.i = ((unsigned int)u) << 16; return v.f;
}
static __device__ __forceinline__ unsigned short f2b(float f) {
    union { float f; unsigned int i; } v; v.f = f;
    unsigned int i = v.i;
    return (unsigned short)((i + 0x7fffu + ((i >> 16) & 1u)) >> 16);
}
static __device__ __forceinline__ u16b f2h_bits(float f) {
    union { _Float16 h; u16b u; } v; v.h = (_Float16)f; return v.u;
}
// packed RNE f32x2 -> bf16x2 (hardware cvt; 1 instr for 2 elements)
static __device__ __forceinline__ unsigned int cvt_pk_bf16(float lo, float hi) {
    unsigned int r;
    asm("v_cvt_pk_bf16_f32 %0, %1, %2" : "=v"(r) : "v"(lo), "v"(hi));
    return r;
}

// Standard swizzled fragment layout for 16x16x32 MFMA operands (16-bit dtypes).
__device__ __forceinline__ int swz(int k, int rc, int CB) {
    return (((k >> 5) * CB + (rc >> 4)) * 64 + ((k >> 3) & 3) * 16 + (rc & 15)) * 8 + (k & 7);
}
// Permuted swizzle for G': k-slot (q,j) <-> m_local = (j>>2)*16 + q*4 + (j&3).
__device__ __forceinline__ int gswz(int m, int o) {
    int kb = m >> 5, mm = m & 31;
    int qs = (mm >> 2) & 3;
    int js = ((mm >> 4) & 1) * 4 + (mm & 3);
    return ((kb * 8 + (o >> 4)) * 64 + qs * 16 + (o & 15)) * 8 + js;
}

// ---------- Phase 0: weights -> fp16 (theta/phi/g) and bf16 (mask) --------------
__global__ __launch_bounds__(256) void prep_kernel(
    const float* __restrict__ wt, const float* __restrict__ wp,
    const float* __restrict__ wg, const float* __restrict__ wm,
    u16b* __restrict__ wF, u16b* __restrict__ wmB)
{
    int t = blockIdx.x * 256 + threadIdx.x;   // grid 128 -> 32768 = HID*CC
    wF[t]         = f2h_bits(wt[t]);
    wF[32768 + t] = f2h_bits(wp[t] * PHI_SCALE);
    wF[65536 + t] = f2h_bits(wg[t]);
    wmB[t]        = f2b(wm[t]);
}

// ---------- Phase 1: Theta/Phi (fp16, swizzled) and G (bf16, perm-swizzled) -----
// All MFMAs fp16 single-pass (2^-11 operand precision).
__global__ __launch_bounds__(256) void proj_kernel(
    const float* __restrict__ x, const u16b* __restrict__ wF,
    u16b* __restrict__ thetaF, u16b* __restrict__ phiF, u16b* __restrict__ gB)
{
    int wave = blockIdx.x * 4 + (threadIdx.x >> 6);   // 2048 waves
    int lane = threadIdx.x & 63;
    int l15 = lane & 15, q = lane >> 4;
    int b = wave >> 9;
    int rem = wave & 511;
    int ntile = rem >> 1;
    int half = rem & 1;                                // ot range half*4..half*4+3
    int n0 = ntile << 4;
    const float* xb = x + (size_t)b * CC * NN;

    f4v acc[3][4];
#pragma unroll
    for (int m = 0; m < 3; m++)
#pragma unroll
        for (int i = 0; i < 4; i++) acc[m][i] = (f4v){0.f, 0.f, 0.f, 0.f};

    float xv[8];
    {
        const float* xp = xb + (size_t)(q * 8) * NN + n0 + l15;
#pragma unroll
        for (int j = 0; j < 8; j++) xv[j] = xp[(size_t)j * NN];
    }

    for (int kc = 0; kc < 8; kc++) {
        int c0 = kc * 32;
        float xn[8];
        if (kc < 7) {
            const float* xp = xb + (size_t)(c0 + 32 + q * 8) * NN + n0 + l15;
#pragma unroll
            for (int j = 0; j < 8; j++) xn[j] = xp[(size_t)j * NN];
        }
        h8v bx;
#pragma unroll
        for (int j = 0; j < 8; j++) bx[j] = (_Float16)xv[j];
#pragma unroll
        for (int mat = 0; mat < 3; mat++) {
#pragma unroll
            for (int otl = 0; otl < 4; otl++) {
                int ot = half * 4 + otl;
                const h8v* ap = reinterpret_cast<const h8v*>(
                    wF + mat * 32768 + (ot * 16 + l15) * CC + c0 + q * 8);
                acc[mat][otl] = __builtin_amdgcn_mfma_f32_16x16x32_f16(*ap, bx, acc[mat][otl], 0, 0, 0);
            }
        }
        if (kc < 7) {
#pragma unroll
            for (int j = 0; j < 8; j++) xv[j] = xn[j];
        }
    }

    size_t boff = (size_t)b * (NN * HIDD);
#pragma unroll
    for (int otl = 0; otl < 4; otl++) {
#pragma unroll
        for (int r = 0; r < 4; r++) {
            int o = (half * 4 + otl) * 16 + q * 4 + r;   // C/D row (hid)
            int n = n0 + l15;                             // C/D col (spatial)
            int offTP = swz(o, n, NN / 16);
            thetaF[boff + offTP] = f2h_bits(acc[0][otl][r]);
            phiF[boff + offTP]   = f2h_bits(acc[1][otl][r]);
            gB[boff + gswz(n, o)] = f2b(acc[2][otl][r]);  // bf16: G' needs range
        }
    }
}

// ---------- small path Phase 2: Lraw[m] = sum_n e^{s[n][m]} (fp16 S) ------------
__global__ __launch_bounds__(256, 2) void stats_kernel(
    const u16b* __restrict__ thetaF, const u16b* __restrict__ phiF,
    float* __restrict__ Lraw)
{
    int xcd = blockIdx.x & 7;                  // grid 1024
    int inner = blockIdx.x >> 3;               // 0..127
    int b = xcd >> 1;
    int su = (xcd & 1) * 128 + inner;          // 0..255 within batch
    int w = threadIdx.x >> 6;
    int wu = su * 4 + w;                       // 0..1023
    int mg = wu >> 4;                          // 64 groups of 4 mtiles
    int ns = wu & 15;                          // 16-way n-split
    int lane = threadIdx.x & 63;

    size_t boff = (size_t)b * (NN * HIDD);
    const u16b* thF = thetaF + boff;
    const u16b* phF = phiF + boff;

    h8v pB[4][4];
#pragma unroll
    for (int mt = 0; mt < 4; mt++)
#pragma unroll
        for (int kb = 0; kb < 4; kb++)
            pB[mt][kb] = *reinterpret_cast<const h8v*>(phF + ((kb * 256 + (mg * 4 + mt)) * 64 + lane) * 8);

    float Lp[4];
#pragma unroll
    for (int i = 0; i < 4; i++) Lp[i] = 0.f;

    for (int i = 0; i < 16; i++) {
        int ntile = ns * 16 + i;
        h8v tA[4];
#pragma unroll
        for (int kb = 0; kb < 4; kb++)
            tA[kb] = *reinterpret_cast<const h8v*>(thF + ((kb * 256 + ntile) * 64 + lane) * 8);
#pragma unroll
        for (int mt = 0; mt < 4; mt++) {
            f4v s = (f4v){0.f, 0.f, 0.f, 0.f};
#pragma unroll
            for (int kb = 0; kb < 4; kb++)
                s = __builtin_amdgcn_mfma_f32_16x16x32_f16(tA[kb], pB[mt][kb], s, 0, 0, 0);
            Lp[mt] += (fexp(s[0]) + fexp(s[1])) + (fexp(s[2]) + fexp(s[3]));
        }
    }
#pragma unroll
    for (int mt = 0; mt < 4; mt++) {
        float v = Lp[mt];
        v += __shfl_xor(v, 16);
        v += __shfl_xor(v, 32);
        if (lane < 16) atomicAdd(&Lraw[b * NN + (mg * 4 + mt) * 16 + lane], v);
    }
}

// ---------- small path Phase 2b: G'[m,o] = G[m,o] / L[m] ------------------------
__global__ __launch_bounds__(256) void rescale_kernel(
    u16b* __restrict__ gB, const float* __restrict__ Lraw)
{
    int t = blockIdx.x * 256 + threadIdx.x;    // grid 1024
    int flat0 = t * 8;
    int b = flat0 >> 19;
    int rem = flat0 & ((NN * HIDD) - 1);
    int kb = rem >> 12;
    int lane = (rem >> 3) & 63;
    int qs = lane >> 4;
    int mbase = kb * 32 + qs * 4;
    const float* Lp = Lraw + b * NN + mbase;
    u16b* gp = gB + flat0;
    s8v g = *reinterpret_cast<const s8v*>(gp);
    s8v o;
#pragma unroll
    for (int j = 0; j < 8; j++) {
        float v = b2f((unsigned short)g[j]) / Lp[((j >> 2) << 4) + (j & 3)];
        o[j] = (short)f2b(v);
    }
    *reinterpret_cast<s8v*>(gp) = o;
}

// ---------- small path Phase 3: Out += softmax(S) @ G' (fp16 S, bf16 PV) --------
__global__ __launch_bounds__(256, 2) void attn_kernel(
    const u16b* __restrict__ thetaF, const u16b* __restrict__ phiF,
    const u16b* __restrict__ gB, float* __restrict__ outAcc)
{
    int xcd = blockIdx.x & 7;                  // grid 1024
    int inner = blockIdx.x >> 3;               // 0..127
    int combo = xcd * 4 + (inner & 3);         // 0..31 = b*8+ms (XCD-pinned)
    int b = combo >> 3;
    int ms = combo & 7;                        // 8-way m-split
    int ng = inner >> 2;                       // 0..31
    int w = threadIdx.x >> 6;
    int lane = threadIdx.x & 63;
    int l15 = lane & 15, q = lane >> 4;
    int ntile0 = ng * 8 + w * 2;

    size_t boff = (size_t)b * (NN * HIDD);
    const u16b* thF = thetaF + boff;
    const u16b* phF = phiF + boff;
    const u16b* gp = gB + boff;

    h8v tB[2][4];
#pragma unroll
    for (int nt = 0; nt < 2; nt++)
#pragma unroll
        for (int kb = 0; kb < 4; kb++)
            tB[nt][kb] = *reinterpret_cast<const h8v*>(thF + ((kb * 256 + ntile0 + nt) * 64 + lane) * 8);

    f4v acc[2][8];
#pragma unroll
    for (int nt = 0; nt < 2; nt++)
#pragma unroll
        for (int i = 0; i < 8; i++) acc[nt][i] = (f4v){0.f, 0.f, 0.f, 0.f};

    for (int mt = 0; mt < 16; mt++) {
        int m0 = ms * 512 + mt * 32;
        s8v pf[2];
#pragma unroll
        for (int h = 0; h < 2; h++) {
            int mtile = (m0 >> 4) + h;
            h8v pA[4];
#pragma unroll
            for (int kb = 0; kb < 4; kb++)
                pA[kb] = *reinterpret_cast<const h8v*>(phF + ((kb * 256 + mtile) * 64 + lane) * 8);
#pragma unroll
            for (int nt = 0; nt < 2; nt++) {
                f4v s = (f4v){0.f, 0.f, 0.f, 0.f};
#pragma unroll
                for (int kb = 0; kb < 4; kb++)
                    s = __builtin_amdgcn_mfma_f32_16x16x32_f16(pA[kb], tB[nt][kb], s, 0, 0, 0);
#pragma unroll
                for (int r = 0; r < 4; r++)
                    pf[nt][h * 4 + r] = (short)f2b(fexp(s[r]));
            }
        }
        int kb2 = m0 >> 5;
#pragma unroll
        for (int ot = 0; ot < 8; ot++) {
            s8v gf = *reinterpret_cast<const s8v*>(gp + ((kb2 * 8 + ot) * 64 + lane) * 8);
#pragma unroll
            for (int nt = 0; nt < 2; nt++)
                acc[nt][ot] = __builtin_amdgcn_mfma_f32_16x16x32_bf16(pf[nt], gf, acc[nt][ot], 0, 0, 0);
        }
    }

    float* oa = outAcc + (size_t)b * (NN * HIDD);
#pragma unroll
    for (int nt = 0; nt < 2; nt++) {
        int n_base = (ntile0 + nt) * 16;
#pragma unroll
        for (int ot = 0; ot < 8; ot++) {
#pragma unroll
            for (int r = 0; r < 4; r++) {
                int n = n_base + q * 4 + r;
                int o = ot * 16 + l15;
                atomicAdd(&oa[swz(o, n, NN / 16)], acc[nt][ot][r]);
            }
        }
    }
}

// ---------- big path Phase 2: S-pass fp16, pipelined, full 16B P stores ---------
// round-4 structure (4 blocks/CU, 2-stage shfl + 20 KB padded LDS Lacc); exp via
// fexp(). Normal (cached) P stores — P stays L3-resident for pv (round-10 lesson).
__global__ __launch_bounds__(256, 4) void spass_kernel(
    const u16b* __restrict__ thetaF, const u16b* __restrict__ phiF,
    u16b* __restrict__ P, float* __restrict__ Lpart)
{
    int xcd = blockIdx.x & 7;                  // grid 2048
    int inner = blockIdx.x >> 3;               // 0..255
    int combo = xcd * 8 + (inner & 7);         // 0..63 = b*16+ms
    int b = combo >> 4;
    int ms = combo & 15;                       // 16-way m-split
    int ng = inner >> 3;                       // 0..31
    int w = threadIdx.x >> 6;
    int lane = threadIdx.x & 63;
    int l15 = lane & 15, q = lane >> 4;
    int ntile0 = ng * 8 + w * 2;

    size_t boff = (size_t)b * (NN * HIDD);
    const u16b* thF = thetaF + boff;
    const u16b* phF = phiF + boff;
    u16b* Pb = P + (size_t)b * NN * NN;

    // [w][m_local(256)][group(4)] stride 5 words. 20 KB.
    __shared__ float Lacc3[4 * 256 * 5];

    h8v tB[2][4];
#pragma unroll
    for (int nt = 0; nt < 2; nt++)
#pragma unroll
        for (int kb = 0; kb < 4; kb++)
            tB[nt][kb] = *reinterpret_cast<const h8v*>(thF + ((kb * 256 + ntile0 + nt) * 64 + lane) * 8);

    int ph = ng & 7;                           // stagger phase (kb2 granularity)
    h8v pA[4];
    {
        int mtile = ms * 16 + ph * 2;          // i2=0, h=0
#pragma unroll
        for (int kb = 0; kb < 4; kb++)
            pA[kb] = *reinterpret_cast<const h8v*>(phF + ((kb * 256 + mtile) * 64 + lane) * 8);
    }

    for (int i2 = 0; i2 < 8; i2++) {
        int mtr = (i2 + ph) & 7;
        unsigned int p000, p001, p010, p011;   // nt=0: h0 pair, h1 pair
        unsigned int p100, p101, p110, p111;   // nt=1
#pragma unroll
        for (int h = 0; h < 2; h++) {
            // prefetch next half-tile's phi (wraps harmlessly on last iter)
            int nmtile = (h == 0) ? (ms * 16 + mtr * 2 + 1)
                                  : (ms * 16 + (((i2 + 1 + ph) & 7)) * 2);
            h8v pAN[4];
#pragma unroll
            for (int kb = 0; kb < 4; kb++)
                pAN[kb] = *reinterpret_cast<const h8v*>(phF + ((kb * 256 + nmtile) * 64 + lane) * 8);
            // S^T tile for both ntiles (fp16, interleaved)
            f4v s0 = (f4v){0.f, 0.f, 0.f, 0.f};
            f4v s1 = (f4v){0.f, 0.f, 0.f, 0.f};
#pragma unroll
            for (int kb = 0; kb < 4; kb++) {
                s0 = __builtin_amdgcn_mfma_f32_16x16x32_f16(pA[kb], tB[0][kb], s0, 0, 0, 0);
                s1 = __builtin_amdgcn_mfma_f32_16x16x32_f16(pA[kb], tB[1][kb], s1, 0, 0, 0);
            }
            float ev0[4], ev1[4];
#pragma unroll
            for (int r = 0; r < 4; r++) {
                ev0[r] = fexp(s0[r]);
                ev1[r] = fexp(s1[r]);
            }
            // packed HW bf16 convert (RNE), 1 instr per 2 values
            if (h == 0) {
                p000 = cvt_pk_bf16(ev0[0], ev0[1]);
                p001 = cvt_pk_bf16(ev0[2], ev0[3]);
                p100 = cvt_pk_bf16(ev1[0], ev1[1]);
                p101 = cvt_pk_bf16(ev1[2], ev1[3]);
            } else {
                p010 = cvt_pk_bf16(ev0[0], ev0[1]);
                p011 = cvt_pk_bf16(ev0[2], ev0[3]);
                p110 = cvt_pk_bf16(ev1[0], ev1[1]);
                p111 = cvt_pk_bf16(ev1[2], ev1[3]);
            }
            // column partial: nt-sum, then 2-stage shfl reduce over l15 pairs
            int tloc = mtr * 32 + h * 16 + q * 4;
            float cs[4];
#pragma unroll
            for (int r = 0; r < 4; r++) {
                cs[r] = ev0[r] + ev1[r];
                cs[r] += __shfl_xor(cs[r], 1);
                cs[r] += __shfl_xor(cs[r], 2);
            }
            if ((l15 & 3) == 0) {
#pragma unroll
                for (int r = 0; r < 4; r++)
                    Lacc3[(w * 256 + tloc + r) * 5 + (l15 >> 2)] = cs[r];
            }
            // rotate prefetch registers
#pragma unroll
            for (int kb = 0; kb < 4; kb++) pA[kb] = pAN[kb];
        }
        // full 16B store per kb2 (both halves assembled)
        int kb2 = ms * 8 + mtr;
        u4v pf0 = (u4v){p000, p001, p010, p011};
        u4v pf1 = (u4v){p100, p101, p110, p111};
        *reinterpret_cast<u4v*>(Pb + ((size_t)(kb2 * 256 + ntile0 + 0) * 64 + lane) * 8) = pf0;
        *reinterpret_cast<u4v*>(Pb + ((size_t)(kb2 * 256 + ntile0 + 1) * 64 + lane) * 8) = pf1;
    }
    __syncthreads();
    {
        int t = threadIdx.x;                   // 0..255 == m_local
        float s = 0.f;
#pragma unroll
        for (int w4 = 0; w4 < 4; w4++) {
            float ps = 0.f;
#pragma unroll
            for (int j = 0; j < 4; j++)
                ps += Lacc3[(w4 * 256 + t) * 5 + j];
            s += ps;
        }
        Lpart[((size_t)(combo * 32 + ng)) * 256 + t] = s;
    }
}

// ---------- big path Phase 2b: fused L-sum + G rescale --------------------------
__global__ __launch_bounds__(256) void lrescale_kernel(
    u16b* __restrict__ gB, const float* __restrict__ Lpart)
{
    int t = blockIdx.x;                        // grid 1024
    int b = t >> 8;
    int kb = (t & 255) >> 1;                   // m>>5, 0..127
    int combo = b * 16 + (kb >> 3);
    int mlbase = (kb & 7) * 32;
    __shared__ float sLp[32][9];
    __shared__ float sL[32];
    int ti = threadIdx.x;
    {
        int mi = ti & 31;                      // = qs*8 + h*4 + r
        int ngp = ti >> 5;                     // 0..7
        int qs = mi >> 3, h = (mi >> 2) & 1, r = mi & 3;
        int ml = mlbase + qs * 4 + h * 16 + r;
        const float* base = Lpart + ((size_t)(combo * 32 + ngp * 4)) * 256 + ml;
        sLp[mi][ngp] = (base[0] + base[256]) + (base[512] + base[768]);
    }
    __syncthreads();
    if (ti < 32) {
        float s = 0.f;
#pragma unroll
        for (int k = 0; k < 8; k++) s += sLp[ti][k];
        sL[ti] = s;
    }
    __syncthreads();
    size_t flat0 = (size_t)b * (NN * HIDD) + (size_t)(t & 255) * 2048 + (size_t)ti * 8;
    int lane = ti & 63;
    int qs = lane >> 4;
    u16b* gp = gB + flat0;
    s8v g = *reinterpret_cast<const s8v*>(gp);
    s8v o;
#pragma unroll
    for (int j = 0; j < 8; j++) {
        int mi = qs * 8 + ((j >> 2) << 2) + (j & 3);
        float v = b2f((unsigned short)g[j]) / sL[mi];
        o[j] = (short)f2b(v);
    }
    *reinterpret_cast<s8v*>(gp) = o;
}

// ---------- big path Phase 3: partial[ms] = P-slice @ G' (NO atomics) -----------
// v3 (measured ~31 us, rounds 2-4/8). 4 waves share g via a 4-slot x 8KB LDS
// ring (global_load_lds, each wave issues 2 of 8 fragments); P is a per-wave
// VGPR stream in 4 named registers. Counted s_waitcnt vmcnt(6) + raw s_barrier
// publishes gll completions (m201 pattern); slot overwrite is issued two
// barriers after that slot's last read (WAR-safe). Normal (cached) P loads —
// P is L3-resident from spass (round-10: nt loads forced HBM, 31->42us).
// (256,4)+deeper-ring variant REGRESSED (round 5): VGPR cap re-serializes.
__global__ __launch_bounds__(256, 3) void pv_kernel(
    const u16b* __restrict__ P, const u16b* __restrict__ gB, u16b* __restrict__ pvPart)
{
    int xcd = blockIdx.x & 7;                  // grid 1024
    int inner = blockIdx.x >> 3;               // 0..127
    int combo = xcd * 2 + (inner & 1);         // 0..15 = b*4+ms (XCD-pinned)
    int b = combo >> 2;
    int ms = combo & 3;                        // 4-way m-split
    int ng = inner >> 1;                       // 0..63
    int w = threadIdx.x >> 6;
    int lane = threadIdx.x & 63;
    int l15 = lane & 15, q = lane >> 4;
    int ntile = ng * 4 + w;                    // 0..255, one ntile per wave

    const u16b* Pb = P + (size_t)b * NN * NN;
    const u16b* gp = gB + (size_t)b * (NN * HIDD);

    __shared__ __align__(16) u16b gS[4 * 8 * 512];   // 4 slots x 8 frags x 1KB = 32 KB

    f4v acc[8];
#pragma unroll
    for (int i = 0; i < 8; i++) acc[i] = (f4v){0.f, 0.f, 0.f, 0.f};

    int ph = ng & 31;                          // stagger phase
    int ot0 = w * 2;                           // this wave's 2 g fragments

    s8v p0, p1, p2, p3;                        // static P ring (rule #20)

#define PV_KB2(it) (ms * 32 + (((it) + ph) & 31))
#define PV_ISSUE(it, sl, preg) do {                                              \
    int kb2_ = PV_KB2(it);                                                       \
    const u16b* s0_ = gp + (((size_t)(kb2_ * 8 + ot0) * 64 + lane) * 8);         \
    __builtin_amdgcn_global_load_lds(                                            \
        (const __attribute__((address_space(1))) unsigned int*)s0_,              \
        (__attribute__((address_space(3))) unsigned int*)(&gS[((sl) * 8 + ot0) * 512]), \
        16, 0, 0);                                                               \
    __builtin_amdgcn_global_load_lds(                                            \
        (const __attribute__((address_space(1))) unsigned int*)(s0_ + 512),      \
        (__attribute__((address_space(3))) unsigned int*)(&gS[((sl) * 8 + ot0 + 1) * 512]), \
        16, 0, 0);                                                               \
    preg = *reinterpret_cast<const s8v*>(                                        \
        Pb + ((size_t)(kb2_ * 256 + ntile) * 64 + lane) * 8);                    \
} while (0)

#define PV_STEP(it, sl, pcons, pnew) do {                                        \
    PV_ISSUE((it) + 2, ((sl) + 2) & 3, pnew);                                    \
    __builtin_amdgcn_sched_barrier(0);                                           \
    asm volatile("s_waitcnt vmcnt(6)" ::: "memory");                             \
    __builtin_amdgcn_sched_barrier(0);                                           \
    __builtin_amdgcn_s_barrier();                                                \
    __builtin_amdgcn_sched_barrier(0);                                           \
    const s8v* gs_ = reinterpret_cast<const s8v*>(gS) + (sl) * 512 + lane;       \
    s8v g0_ = gs_[0];   s8v g1_ = gs_[64];  s8v g2_ = gs_[128]; s8v g3_ = gs_[192]; \
    s8v g4_ = gs_[256]; s8v g5_ = gs_[320]; s8v g6_ = gs_[384]; s8v g7_ = gs_[448]; \
    acc[0] = __builtin_amdgcn_mfma_f32_16x16x32_bf16(pcons, g0_, acc[0], 0, 0, 0); \
    acc[1] = __builtin_amdgcn_mfma_f32_16x16x32_bf16(pcons, g1_, acc[1], 0, 0, 0); \
    acc[2] = __builtin_amdgcn_mfma_f32_16x16x32_bf16(pcons, g2_, acc[2], 0, 0, 0); \
    acc[3] = __builtin_amdgcn_mfma_f32_16x16x32_bf16(pcons, g3_, acc[3], 0, 0, 0); \
    acc[4] = __builtin_amdgcn_mfma_f32_16x16x32_bf16(pcons, g4_, acc[4], 0, 0, 0); \
    acc[5] = __builtin_amdgcn_mfma_f32_16x16x32_bf16(pcons, g5_, acc[5], 0, 0, 0); \
    acc[6] = __builtin_amdgcn_mfma_f32_16x16x32_bf16(pcons, g6_, acc[6], 0, 0, 0); \
    acc[7] = __builtin_amdgcn_mfma_f32_16x16x32_bf16(pcons, g7_, acc[7], 0, 0, 0); \
} while (0)

    // prologue: 2 iterations in flight (6 VMEM ops)
    PV_ISSUE(0, 0, p0);
    PV_ISSUE(1, 1, p1);

    for (int i8 = 0; i8 < 32; i8 += 4) {
        PV_STEP(i8 + 0, 0, p0, p2);
        PV_STEP(i8 + 1, 1, p1, p3);
        PV_STEP(i8 + 2, 2, p2, p0);
        PV_STEP(i8 + 3, 3, p3, p1);
    }
#undef PV_STEP
#undef PV_ISSUE
#undef PV_KB2

    u16b* pp = pvPart + (size_t)ms * ((size_t)BB * NN * HIDD) + (size_t)b * (NN * HIDD);
    int n_base = ntile * 16;
#pragma unroll
    for (int ot = 0; ot < 8; ot++) {
#pragma unroll
        for (int r = 0; r < 4; r++) {
            int n = n_base + q * 4 + r;
            int o = ot * 16 + l15;
            pp[swz(o, n, NN / 16)] = f2b(acc[ot][r]);
        }
    }
}

// ---------- big path Phase 4: y = x + w_mask @ (sum of partials)^T --------------
__global__ __launch_bounds__(256) void final_big_kernel(
    const float* __restrict__ x, const u16b* __restrict__ wmB,
    const u16b* __restrict__ pvPart, float* __restrict__ y)
{
    int wave = blockIdx.x * 4 + (threadIdx.x >> 6);   // 4096 waves
    int lane = threadIdx.x & 63;
    int l15 = lane & 15, q = lane >> 4;
    int b = wave >> 10;
    int rem = wave & 1023;
    int ctile = rem >> 6;
    int n64 = rem & 63;
    const size_t pstride = (size_t)BB * NN * HIDD;
    const u16b* pb = pvPart + (size_t)b * (NN * HIDD);
    const float* xb = x + (size_t)b * CC * NN;
    float* yb = y + (size_t)b * CC * NN;
    int c0 = ctile * 16;

    s8v aB[4];
#pragma unroll
    for (int kb = 0; kb < 4; kb++)
        aB[kb] = *reinterpret_cast<const s8v*>(wmB + (c0 + l15) * HIDD + kb * 32 + q * 8);

#pragma unroll
    for (int nt = 0; nt < 4; nt++) {
        int ntile = n64 * 4 + nt;
        f4v acc = (f4v){0.f, 0.f, 0.f, 0.f};
#pragma unroll
        for (int kb = 0; kb < 4; kb++) {
            size_t fo = ((size_t)(kb * 256 + ntile) * 64 + lane) * 8;
            // issue all 4 partial loads together, then convert+sum
            s8v v0 = *reinterpret_cast<const s8v*>(pb + 0 * pstride + fo);
            s8v v1 = *reinterpret_cast<const s8v*>(pb + 1 * pstride + fo);
            s8v v2 = *reinterpret_cast<const s8v*>(pb + 2 * pstride + fo);
            s8v v3 = *reinterpret_cast<const s8v*>(pb + 3 * pstride + fo);
            s8v bv;
#pragma unroll
            for (int j = 0; j < 8; j++) {
                float s = (b2f((unsigned short)v0[j]) + b2f((unsigned short)v1[j]))
                        + (b2f((unsigned short)v2[j]) + b2f((unsigned short)v3[j]));
                bv[j] = (short)f2b(s);
            }
            acc = __builtin_amdgcn_mfma_f32_16x16x32_bf16(aB[kb], bv, acc, 0, 0, 0);
        }
#pragma unroll
        for (int r = 0; r < 4; r++) {
            int c = c0 + q * 4 + r;
            int n = ntile * 16 + l15;
            size_t idx = (size_t)c * NN + n;
            yb[idx] = xb[idx] + acc[r];
        }
    }
}

// ---------- small path Phase 4: y = x + w_mask @ Out^T --------------------------
__global__ __launch_bounds__(256) void final_kernel(
    const float* __restrict__ x, const u16b* __restrict__ wmB,
    const float* __restrict__ outAcc, float* __restrict__ y)
{
    int wave = blockIdx.x * 4 + (threadIdx.x >> 6);   // 4096 waves
    int lane = threadIdx.x & 63;
    int l15 = lane & 15, q = lane >> 4;
    int b = wave >> 10;
    int rem = wave & 1023;
    int ctile = rem >> 6;
    int n64 = rem & 63;
    const float* oa = outAcc + (size_t)b * (NN * HIDD);
    const float* xb = x + (size_t)b * CC * NN;
    float* yb = y + (size_t)b * CC * NN;
    int c0 = ctile * 16;

    s8v aB[4];
#pragma unroll
    for (int kb = 0; kb < 4; kb++)
        aB[kb] = *reinterpret_cast<const s8v*>(wmB + (c0 + l15) * HIDD + kb * 32 + q * 8);

#pragma unroll
    for (int nt = 0; nt < 4; nt++) {
        int ntile = n64 * 4 + nt;
        f4v acc = (f4v){0.f, 0.f, 0.f, 0.f};
#pragma unroll
        for (int kb = 0; kb < 4; kb++) {
            const float* bp = oa + ((size_t)(kb * 256 + ntile) * 64 + lane) * 8;
            f4v b0 = *reinterpret_cast<const f4v*>(bp);
            f4v b1 = *reinterpret_cast<const f4v*>(bp + 4);
            s8v bv;
#pragma unroll
            for (int j = 0; j < 4; j++) {
                bv[j]     = (short)f2b(b0[j]);
                bv[j + 4] = (short)f2b(b1[j]);
            }
            acc = __builtin_amdgcn_mfma_f32_16x16x32_bf16(aB[kb], bv, acc, 0, 0, 0);
        }
#pragma unroll
        for (int r = 0; r < 4; r++) {
            int c = c0 + q * 4 + r;
            int n = ntile * 16 + l15;
            size_t idx = (size_t)c * NN + n;
            yb[idx] = xb[idx] + acc[r];
        }
    }
}

extern "C" void kernel_launch(void* const* d_in, const int* in_sizes, int n_in,
                              void* d_out, int out_size, void* d_ws, size_t ws_size,
                              hipStream_t stream)
{
    (void)in_sizes; (void)n_in; (void)out_size;
    const float* x  = (const float*)d_in[0];
    const float* wt = (const float*)d_in[1];
    const float* wp = (const float*)d_in[2];
    const float* wg = (const float*)d_in[3];
    const float* wm = (const float*)d_in[4];
    float* y = (float*)d_out;

    char* ws = (char*)d_ws;
    const size_t MB = 1 << 20;
    u16b* thetaF = (u16b*)(ws + 0 * MB);                   // 4 MB
    u16b* phiF   = (u16b*)(ws + 4 * MB);                   // 4 MB
    u16b* pvPart = (u16b*)(ws + 0 * MB);                   // 16 MB, overlays theta/phi (dead after spass)
    u16b* gB     = (u16b*)(ws + 16 * MB);                  // 4 MB
    float* outAcc = (float*)(ws + 20 * MB);                // 8 MB fp32 (small path)
    float* Lraw   = (float*)(ws + 28 * MB);                // 64 KB (small path)
    char* wbase = ws + 28 * MB + (64 << 10);
    u16b* wF  = (u16b*)(wbase);                            // 192 KB (theta+phi+g fp16)
    u16b* wmB = (u16b*)(wbase + (192 << 10));              // 64 KB
    float* Lpart = (float*)(ws + 30 * MB);                 // 2 MB (big path)
    u16b* P   = (u16b*)(ws + 32 * MB);                     // 134.2 MB (big path)

    const size_t need_big = 32 * MB + (size_t)BB * NN * NN * sizeof(u16b);
    const bool big = ws_size >= need_big;

    hipLaunchKernelGGL(prep_kernel, dim3(128), dim3(256), 0, stream,
                       wt, wp, wg, wm, wF, wmB);
    hipLaunchKernelGGL(proj_kernel, dim3(512), dim3(256), 0, stream,
                       x, wF, thetaF, phiF, gB);

    if (big) {
        hipLaunchKernelGGL(spass_kernel,    dim3(2048), dim3(256), 0, stream,
                           thetaF, phiF, P, Lpart);
        hipLaunchKernelGGL(lrescale_kernel, dim3(1024), dim3(256), 0, stream, gB, Lpart);
        // pv overwrites the theta/phi region (dead after spass) with bf16 partials
        hipLaunchKernelGGL(pv_kernel,       dim3(1024), dim3(256), 0, stream, P, gB, pvPart);
        hipLaunchKernelGGL(final_big_kernel, dim3(1024), dim3(256), 0, stream,
                           x, wmB, pvPart, y);
    } else {
        hipMemsetAsync(Lraw, 0, (size_t)BB * NN * sizeof(float), stream);
        hipMemsetAsync(outAcc, 0, (size_t)BB * NN * HIDD * sizeof(float), stream);
        hipLaunchKernelGGL(stats_kernel,   dim3(1024), dim3(256), 0, stream,
                           thetaF, phiF, Lraw);
        hipLaunchKernelGGL(rescale_kernel, dim3(1024), dim3(256), 0, stream, gB, Lraw);
        hipLaunchKernelGGL(attn_kernel,    dim3(1024), dim3(256), 0, stream,
                           thetaF, phiF, gB, outAcc);
        hipLaunchKernelGGL(final_kernel,   dim3(1024), dim3(256), 0, stream,
                           x, wmB, outAcc, y);
    }
}